// Round 12
// baseline (1373.686 us; speedup 1.0000x reference)
//
#include <hip/hip_runtime.h>
#include <math.h>

#define BB 128
#define QQ 200
#define CC 92
#define CMPAD (QQ * QQ + 64) // pad so c3 = crow[192+t] stays in-bounds for t<64

// ---------------------------------------------------------------------------
__device__ __forceinline__ int rdlane_i(int x, int l) { return __builtin_amdgcn_readlane(x, l); }
__device__ __forceinline__ float rdlane_f(float x, int l) {
    return __uint_as_float((unsigned)__builtin_amdgcn_readlane((int)__float_as_uint(x), l));
}

// wave64 float min-reduce via DPP (row_shr 1/2/4/8, row_bcast 15/31), result
// broadcast from lane 63 as an SGPR. Float domain (v_min_f32): jnp.argmin
// compares floats, so equality-ballot against this min reproduces its
// semantics exactly (incl. -0==+0). No NaNs in this data.
__device__ __forceinline__ float wave_fmin_bcast(float x) {
    float y;
#define DPPSTEP(ctrl) \
    y = __uint_as_float((unsigned)__builtin_amdgcn_update_dpp( \
            (int)__float_as_uint(x), (int)__float_as_uint(x), ctrl, 0xf, 0xf, false)); \
    x = fminf(x, y);
    DPPSTEP(0x111) DPPSTEP(0x112) DPPSTEP(0x114) DPPSTEP(0x118)
    DPPSTEP(0x142) DPPSTEP(0x143)
#undef DPPSTEP
    return rdlane_f(x, 63);
}

// ---------------------------------------------------------------------------
// R21 = R20 (joint vectorized lse + stride-3 producers + two-epoch consumer;
// measured 1317us dispatch, best) with the producer fill BATCHED in groups of
// 4 rows: all 16 pcrow[cls] gathers + 4 pb4 loads issue up-front (16-deep
// MLP amortizes ~600cyc gather latency to ~150cyc/row -- R20 issued them
// per-row behind the previous row's memory-clobber drain, serializing at
// ~0.75us/row), then 4 rows compute+store, ONE lgkmcnt(0) drain, 4 rdy
// publishes. Group loops are fixed-bound (q=0..3, guarded q<nb) so all
// register indexing is compile-time-constant (no scratch). Publish
// granularity coarsens readiness by <=12 rows -- irrelevant past phase ~15.
// Consumer, lse, publish ordering, and all fp expressions byte-for-byte R20
// => trajectory bit-for-bit vs reference.
// Lane t owns columns j = 1+t+64k (k=0..3; k=3 valid only for t<8).
// ---------------------------------------------------------------------------

#define PHASE_BODY(I)                                                          \
    do {                                                                       \
        minv[0] = minv[1] = minv[2] = minv[3] = INF;                           \
        waysl[0] = waysl[1] = waysl[2] = waysl[3] = 0;                         \
        usedm = 0;                                                             \
        usent = 0.f;                                                           \
        int j0 = 0;                                                            \
        float u0 = 0.f;                                                        \
        const float* crow = cm + ((I) - 1) * QQ;                               \
        float c0 = crow[t];                                                    \
        float c1 = crow[64 + t];                                               \
        float c2 = crow[128 + t];                                              \
        float c3 = crow[192 + t];                                              \
        for (;;) {                                                             \
            if (j0 > 0) {                                                      \
                int s = (j0 - 1) >> 6;                                         \
                if (((j0 - 1) & 63) == t) usedm |= 1 << s;                     \
            }                                                                  \
            float kv0, kv1, kv2, kv3;                                          \
            {                                                                  \
                float cur;                                                     \
                cur = c0 - u0 - v[0];                                          \
                if (!(usedm & 1) && cur < minv[0]) { minv[0] = cur; waysl[0] = j0; } \
                kv0 = (usedm & 1) ? INF : minv[0];                             \
                cur = c1 - u0 - v[1];                                          \
                if (!(usedm & 2) && cur < minv[1]) { minv[1] = cur; waysl[1] = j0; } \
                kv1 = (usedm & 2) ? INF : minv[1];                             \
                cur = c2 - u0 - v[2];                                          \
                if (!(usedm & 4) && cur < minv[2]) { minv[2] = cur; waysl[2] = j0; } \
                kv2 = (usedm & 4) ? INF : minv[2];                             \
                cur = c3 - u0 - v[3];                                          \
                if (!(usedm & 8) && t < 8 && cur < minv[3]) { minv[3] = cur; waysl[3] = j0; } \
                kv3 = ((usedm & 8) || t >= 8) ? INF : minv[3];                 \
            }                                                                  \
            float gmin = wave_fmin_bcast(fminf(fminf(kv0, kv1), fminf(kv2, kv3))); \
            float delta = gmin;                                                \
            unsigned long long m0 = __ballot(kv0 == gmin);                     \
            unsigned long long m1 = __ballot(kv1 == gmin);                     \
            unsigned long long m2 = __ballot(kv2 == gmin);                     \
            unsigned long long m3 = __ballot(kv3 == gmin);                     \
            int j1;                                                            \
            if (m0)      j1 = 1   + (int)__builtin_ctzll(m0);                  \
            else if (m1) j1 = 65  + (int)__builtin_ctzll(m1);                  \
            else if (m2) j1 = 129 + (int)__builtin_ctzll(m2);                  \
            else         j1 = 193 + (int)__builtin_ctzll(m3);                  \
            int kk = (j1 - 1) >> 6, ln = (j1 - 1) & 63;                        \
            float us = (kk == 0) ? uslot[0] : (kk == 1) ? uslot[1]             \
                      : (kk == 2) ? uslot[2] : uslot[3];                       \
            int pi = (int)(((unsigned)rdlane_i((int)pp, ln) >> (kk * 8)) & 255u); \
            int nr = (pi > 0 ? pi : 1) - 1;                                    \
            const float* nrow = cm + nr * QQ;                                  \
            float n0 = nrow[t];                                                \
            float n1 = nrow[64 + t];                                           \
            float n2 = nrow[128 + t];                                          \
            float n3 = nrow[192 + t];                                          \
            float u0n = rdlane_f(us, ln);                                      \
            _Pragma("unroll")                                                  \
            for (int k = 0; k < 4; ++k) {                                      \
                if (usedm & (1 << k)) {                                        \
                    v[k] -= delta;                                             \
                    uslot[k] += delta;                                         \
                } else if (k < nval) {                                         \
                    minv[k] -= delta;                                          \
                }                                                              \
            }                                                                  \
            usent += delta;                                                    \
            if (pi == 0) { j0 = j1; break; }                                   \
            j0 = j1; u0 = u0n;                                                 \
            c0 = n0; c1 = n1; c2 = n2; c3 = n3;                                \
        }                                                                      \
        {                                                                      \
            int jj = j0;                                                       \
            while (jj != 0) {                                                  \
                int jm = jj - 1, km = jm >> 6, lm = jm & 63;                   \
                int ws = (km == 0) ? waysl[0] : (km == 1) ? waysl[1]           \
                        : (km == 2) ? waysl[2] : waysl[3];                     \
                int jn = rdlane_i(ws, lm);                                     \
                int pnew; float unew;                                          \
                if (jn == 0) {                                                 \
                    pnew = (I);                                                \
                    unew = usent;                                              \
                } else {                                                       \
                    int jm2 = jn - 1, kn = jm2 >> 6, ln2 = jm2 & 63;           \
                    int   ps2 = (kn == 0) ? pslot[0] : (kn == 1) ? pslot[1]    \
                               : (kn == 2) ? pslot[2] : pslot[3];              \
                    float us2 = (kn == 0) ? uslot[0] : (kn == 1) ? uslot[1]    \
                               : (kn == 2) ? uslot[2] : uslot[3];              \
                    pnew = rdlane_i(ps2, ln2);                                 \
                    unew = rdlane_f(us2, ln2);                                 \
                }                                                              \
                if (lm == t) {                                                 \
                    pslot[km] = pnew;                                          \
                    uslot[km] = unew;                                          \
                    int sh = km * 8;                                           \
                    pp = (pp & ~(255u << sh)) | ((unsigned)pnew << sh);        \
                }                                                              \
                jj = jn;                                                       \
            }                                                                  \
        }                                                                      \
    } while (0)

__global__ __launch_bounds__(256) void hungarian_fused(const float* __restrict__ pc,
                                                       const float* __restrict__ pb,
                                                       const int*   __restrict__ tc,
                                                       const float* __restrict__ tb,
                                                       float* __restrict__ out) {
    const int b = blockIdx.x;
    const int tid = threadIdx.x;
    const int w = tid >> 6;         // wave id 0..3
    const int t = tid & 63;         // lane id

    __shared__ __align__(16) float cm[CMPAD];
    __shared__ float lse_s[QQ];
    __shared__ int rdy[QQ];

    const float INF = 1e9f;
    const int nval = (t < 8) ? 4 : 3;   // slot k valid iff t+64k < 200

    if (tid < QQ) rdy[tid] = 0;

    // ---- joint lse: one row per thread, float4 loads (23 per row; row base
    //      368B = 16B-aligned). fmax/exp/log op ORDER identical to scalar
    //      reference => bit-identical values.
    if (tid < QQ) {
        const float4* row4 = reinterpret_cast<const float4*>(pc + ((size_t)(b * QQ + tid)) * CC);
        float m = -INFINITY;
        for (int c4 = 0; c4 < CC / 4; ++c4) {
            float4 x = row4[c4];
            m = fmaxf(fmaxf(fmaxf(fmaxf(m, x.x), x.y), x.z), x.w);
        }
        float s = 0.f;
        for (int c4 = 0; c4 < CC / 4; ++c4) {
            float4 x = row4[c4];
            s += expf(x.x - m); s += expf(x.y - m);
            s += expf(x.z - m); s += expf(x.w - m);
        }
        lse_s[tid] = m + logf(s);
    }
    __syncthreads();                    // only barrier; all threads reach it

    if (w > 0) {
        // ========== producers: waves 1..3, rows (w-1)+3m, groups of 4 ======
        const int start = w - 1;                    // 0,1,2
        const int count = (QQ - start + 2) / 3;     // 67,67,66

        // per-lane column constants (owned columns j = t+64k)
        int   cls[4];
        float tbx[4][4];
#pragma unroll
        for (int k = 0; k < 4; ++k) {
            if (k < nval) {
                int jj = t + 64 * k;
                cls[k] = tc[b * QQ + jj];
                const float4 v4 = *reinterpret_cast<const float4*>(tb + ((size_t)(b * QQ + jj)) * 4);
                tbx[k][0] = v4.x; tbx[k][1] = v4.y; tbx[k][2] = v4.z; tbx[k][3] = v4.w;
            } else {
                cls[k] = 0;
                tbx[k][0] = tbx[k][1] = tbx[k][2] = tbx[k][3] = 0.f;
            }
        }

        for (int m0 = 0; m0 < count; m0 += 4) {
            const int nb = (count - m0 < 4) ? (count - m0) : 4;

            // ---- issue ALL gathers + pb loads for the group (16-deep MLP)
            float pcv[4][4];
            float4 pb4[4];
            float lsei[4];
            int   ii[4];
#pragma unroll
            for (int q = 0; q < 4; ++q) {
                if (q < nb) {
                    const int i = start + 3 * (m0 + q);
                    ii[q] = i;
                    pb4[q] = *reinterpret_cast<const float4*>(pb + ((size_t)(b * QQ + i)) * 4);
                    lsei[q] = lse_s[i];
                    const float* pcrow = pc + ((size_t)(b * QQ + i)) * CC;
#pragma unroll
                    for (int k = 0; k < 4; ++k) {
                        if (k < nval) pcv[q][k] = pcrow[cls[k]];
                    }
                }
            }

            // ---- compute + store (identical fp expression/order as R14)
#pragma unroll
            for (int q = 0; q < 4; ++q) {
                if (q < nb) {
                    const int i = ii[q];
                    const float pbb[4] = {pb4[q].x, pb4[q].y, pb4[q].z, pb4[q].w};
#pragma unroll
                    for (int k = 0; k < 4; ++k) {
                        if (k < nval) {
                            float ce = lsei[q] - pcv[q][k];
                            float sl1 = 0.f;
#pragma unroll
                            for (int d = 0; d < 4; ++d) {
                                float df = pbb[d] - tbx[k][d];
                                float ad = fabsf(df);
                                sl1 += (ad < 1.f) ? 0.5f * df * df : (ad - 0.5f);
                            }
                            float mask = (cls[k] != 0) ? 1.f : 0.f;
                            cm[i * QQ + t + 64 * k] = ce + sl1 * mask;
                        }
                    }
                }
            }

            // ---- one drain for the group, then publish its rows
            asm volatile("s_waitcnt lgkmcnt(0)" ::: "memory");
            if (t == 0) {
#pragma unroll
                for (int q = 0; q < 4; ++q) {
                    if (q < nb) ((volatile int*)rdy)[ii[q]] = 1;
                }
            }
        }
        return;
    }

    // ================= consumer: wave 0, two-epoch R14 main loop ===========
    float v[4]     = {0.f, 0.f, 0.f, 0.f};
    int   pslot[4] = {0, 0, 0, 0};      // p for owned columns (0 = free)
    unsigned pp    = 0u;                // packed u8 shadow of pslot
    float uslot[4] = {0.f, 0.f, 0.f, 0.f};  // u of row matched to owned column
    float minv[4];
    int   waysl[4];
    int   usedm;
    float usent;
    int   watermark = 0;                // rows 0..watermark-1 known staged
    int   i = 1;

    // catch-up epoch: poll + clobber, only while rows are still landing
    for (; i <= QQ && watermark < QQ; ++i) {
        while (watermark < i) {
            int idx = watermark + t;
            int f = (idx < QQ) ? ((volatile int*)rdy)[idx] : 1;
            unsigned long long rm = __ballot(f != 0);
            unsigned long long nrm = ~rm;   // bit j set => lane j not ready
            int adv = nrm ? (int)__builtin_ctzll(nrm) : 64;
            if (adv == 0) __builtin_amdgcn_s_sleep(8);
            watermark += adv;
        }
        asm volatile("" ::: "memory");  // keep crow reads below the poll
        PHASE_BODY(i);
    }
    // steady epoch: all rows staged; no poll, no branch, no clobber --
    // R14's exact codegen freedom restored
    for (; i <= QQ; ++i) {
        PHASE_BODY(i);
    }

    // pslot[k] = row matched to owned column jc; emit per-row matched cost
#pragma unroll
    for (int k = 0; k < 4; ++k) {
        if (k < nval) {
            int jc = 1 + t + 64 * k;
            int row = pslot[k] - 1;
            out[b * QQ + row] = cm[row * QQ + (jc - 1)];
        }
    }
}

// ---------------------------------------------------------------------------
extern "C" void kernel_launch(void* const* d_in, const int* in_sizes, int n_in,
                              void* d_out, int out_size, void* d_ws, size_t ws_size,
                              hipStream_t stream) {
    const float* pred_cat  = (const float*)d_in[0];
    const float* pred_bbox = (const float*)d_in[1];
    const int*   tar_cat   = (const int*)d_in[2];
    const float* tar_bbox  = (const float*)d_in[3];
    float* out = (float*)d_out;
    (void)d_ws; (void)ws_size;

    hungarian_fused<<<BB, 256, 0, stream>>>(pred_cat, pred_bbox, tar_cat, tar_bbox, out);
}

// Round 13
// 1367.624 us; speedup vs baseline: 1.0044x; 1.0044x over previous
//
#include <hip/hip_runtime.h>
#include <math.h>

#define BB 128
#define QQ 200
#define CC 92
#define CMPAD (QQ * QQ + 64) // pad so c3 = crow[192+t] stays in-bounds for t<64

// ---------------------------------------------------------------------------
__device__ __forceinline__ int rdlane_i(int x, int l) { return __builtin_amdgcn_readlane(x, l); }
__device__ __forceinline__ float rdlane_f(float x, int l) {
    return __uint_as_float((unsigned)__builtin_amdgcn_readlane((int)__float_as_uint(x), l));
}

// wave64 float min-reduce via DPP (row_shr 1/2/4/8, row_bcast 15/31), result
// broadcast from lane 63 as an SGPR. Float domain (v_min_f32): jnp.argmin
// compares floats, so equality-ballot against this min reproduces its
// semantics exactly (incl. -0==+0). No NaNs in this data.
__device__ __forceinline__ float wave_fmin_bcast(float x) {
    float y;
#define DPPSTEP(ctrl) \
    y = __uint_as_float((unsigned)__builtin_amdgcn_update_dpp( \
            (int)__float_as_uint(x), (int)__float_as_uint(x), ctrl, 0xf, 0xf, false)); \
    x = fminf(x, y);
    DPPSTEP(0x111) DPPSTEP(0x112) DPPSTEP(0x114) DPPSTEP(0x118)
    DPPSTEP(0x142) DPPSTEP(0x143)
#undef DPPSTEP
    return rdlane_f(x, 63);
}

// ---------------------------------------------------------------------------
// R22 = R20 verbatim (measured best: total 1367.6us, dispatch 1317us).
// R21's producer batching regressed (+13us): per-group drain delayed the
// FIRST rows' publish, and only the first rows are on the consumer's
// critical path (mid-stream fill already outpaces the solve).
// Structure: joint vectorized lse (all 4 waves, lane-per-row, float4 loads,
// identical op order) -> one barrier -> waves 1-3 stream cost rows stride-3
// (publish per row: lgkmcnt(0) drain then rdy=1) while wave 0 runs the
// two-epoch R14 main loop (catch-up epoch with poll+clobber only while
// watermark<QQ, then clobber-free steady epoch = R14's exact codegen).
// All fp expressions byte-identical to the reference pipeline => cost
// matrix, JV trajectory, and output are bit-for-bit vs reference.
// Main-loop structure (one wave/batch, 128 CUs busy; usedm bitmask, gated
// updates, branchy k-major argmin, packed-u8 pslot shadow `pp`, in-loop
// next-row LDS prefetch) is the survivor of 5 failed structural attacks
// (R10/R11/R15/R16/R17) -- serial-latency plateau: ~15k dependent pops x
// (~85cyc reduce/select chain + ~120cyc LDS row hop). Counters at plateau:
// HBM 0.05%, VALUBusy 4.2%, no throughput resource near limit.
// Lane t owns columns j = 1+t+64k (k=0..3; k=3 valid only for t<8).
// ---------------------------------------------------------------------------

#define PHASE_BODY(I)                                                          \
    do {                                                                       \
        minv[0] = minv[1] = minv[2] = minv[3] = INF;                           \
        waysl[0] = waysl[1] = waysl[2] = waysl[3] = 0;                         \
        usedm = 0;                                                             \
        usent = 0.f;                                                           \
        int j0 = 0;                                                            \
        float u0 = 0.f;                                                        \
        const float* crow = cm + ((I) - 1) * QQ;                               \
        float c0 = crow[t];                                                    \
        float c1 = crow[64 + t];                                               \
        float c2 = crow[128 + t];                                              \
        float c3 = crow[192 + t];                                              \
        for (;;) {                                                             \
            if (j0 > 0) {                                                      \
                int s = (j0 - 1) >> 6;                                         \
                if (((j0 - 1) & 63) == t) usedm |= 1 << s;                     \
            }                                                                  \
            float kv0, kv1, kv2, kv3;                                          \
            {                                                                  \
                float cur;                                                     \
                cur = c0 - u0 - v[0];                                          \
                if (!(usedm & 1) && cur < minv[0]) { minv[0] = cur; waysl[0] = j0; } \
                kv0 = (usedm & 1) ? INF : minv[0];                             \
                cur = c1 - u0 - v[1];                                          \
                if (!(usedm & 2) && cur < minv[1]) { minv[1] = cur; waysl[1] = j0; } \
                kv1 = (usedm & 2) ? INF : minv[1];                             \
                cur = c2 - u0 - v[2];                                          \
                if (!(usedm & 4) && cur < minv[2]) { minv[2] = cur; waysl[2] = j0; } \
                kv2 = (usedm & 4) ? INF : minv[2];                             \
                cur = c3 - u0 - v[3];                                          \
                if (!(usedm & 8) && t < 8 && cur < minv[3]) { minv[3] = cur; waysl[3] = j0; } \
                kv3 = ((usedm & 8) || t >= 8) ? INF : minv[3];                 \
            }                                                                  \
            float gmin = wave_fmin_bcast(fminf(fminf(kv0, kv1), fminf(kv2, kv3))); \
            float delta = gmin;                                                \
            unsigned long long m0 = __ballot(kv0 == gmin);                     \
            unsigned long long m1 = __ballot(kv1 == gmin);                     \
            unsigned long long m2 = __ballot(kv2 == gmin);                     \
            unsigned long long m3 = __ballot(kv3 == gmin);                     \
            int j1;                                                            \
            if (m0)      j1 = 1   + (int)__builtin_ctzll(m0);                  \
            else if (m1) j1 = 65  + (int)__builtin_ctzll(m1);                  \
            else if (m2) j1 = 129 + (int)__builtin_ctzll(m2);                  \
            else         j1 = 193 + (int)__builtin_ctzll(m3);                  \
            int kk = (j1 - 1) >> 6, ln = (j1 - 1) & 63;                        \
            float us = (kk == 0) ? uslot[0] : (kk == 1) ? uslot[1]             \
                      : (kk == 2) ? uslot[2] : uslot[3];                       \
            int pi = (int)(((unsigned)rdlane_i((int)pp, ln) >> (kk * 8)) & 255u); \
            int nr = (pi > 0 ? pi : 1) - 1;                                    \
            const float* nrow = cm + nr * QQ;                                  \
            float n0 = nrow[t];                                                \
            float n1 = nrow[64 + t];                                           \
            float n2 = nrow[128 + t];                                          \
            float n3 = nrow[192 + t];                                          \
            float u0n = rdlane_f(us, ln);                                      \
            _Pragma("unroll")                                                  \
            for (int k = 0; k < 4; ++k) {                                      \
                if (usedm & (1 << k)) {                                        \
                    v[k] -= delta;                                             \
                    uslot[k] += delta;                                         \
                } else if (k < nval) {                                         \
                    minv[k] -= delta;                                          \
                }                                                              \
            }                                                                  \
            usent += delta;                                                    \
            if (pi == 0) { j0 = j1; break; }                                   \
            j0 = j1; u0 = u0n;                                                 \
            c0 = n0; c1 = n1; c2 = n2; c3 = n3;                                \
        }                                                                      \
        {                                                                      \
            int jj = j0;                                                       \
            while (jj != 0) {                                                  \
                int jm = jj - 1, km = jm >> 6, lm = jm & 63;                   \
                int ws = (km == 0) ? waysl[0] : (km == 1) ? waysl[1]           \
                        : (km == 2) ? waysl[2] : waysl[3];                     \
                int jn = rdlane_i(ws, lm);                                     \
                int pnew; float unew;                                          \
                if (jn == 0) {                                                 \
                    pnew = (I);                                                \
                    unew = usent;                                              \
                } else {                                                       \
                    int jm2 = jn - 1, kn = jm2 >> 6, ln2 = jm2 & 63;           \
                    int   ps2 = (kn == 0) ? pslot[0] : (kn == 1) ? pslot[1]    \
                               : (kn == 2) ? pslot[2] : pslot[3];              \
                    float us2 = (kn == 0) ? uslot[0] : (kn == 1) ? uslot[1]    \
                               : (kn == 2) ? uslot[2] : uslot[3];              \
                    pnew = rdlane_i(ps2, ln2);                                 \
                    unew = rdlane_f(us2, ln2);                                 \
                }                                                              \
                if (lm == t) {                                                 \
                    pslot[km] = pnew;                                          \
                    uslot[km] = unew;                                          \
                    int sh = km * 8;                                           \
                    pp = (pp & ~(255u << sh)) | ((unsigned)pnew << sh);        \
                }                                                              \
                jj = jn;                                                       \
            }                                                                  \
        }                                                                      \
    } while (0)

__global__ __launch_bounds__(256) void hungarian_fused(const float* __restrict__ pc,
                                                       const float* __restrict__ pb,
                                                       const int*   __restrict__ tc,
                                                       const float* __restrict__ tb,
                                                       float* __restrict__ out) {
    const int b = blockIdx.x;
    const int tid = threadIdx.x;
    const int w = tid >> 6;         // wave id 0..3
    const int t = tid & 63;         // lane id

    __shared__ __align__(16) float cm[CMPAD];
    __shared__ float lse_s[QQ];
    __shared__ int rdy[QQ];

    const float INF = 1e9f;
    const int nval = (t < 8) ? 4 : 3;   // slot k valid iff t+64k < 200

    if (tid < QQ) rdy[tid] = 0;

    // ---- joint lse: one row per thread, float4 loads (23 per row; row base
    //      368B = 16B-aligned). fmax/exp/log op ORDER identical to scalar
    //      reference => bit-identical values.
    if (tid < QQ) {
        const float4* row4 = reinterpret_cast<const float4*>(pc + ((size_t)(b * QQ + tid)) * CC);
        float m = -INFINITY;
        for (int c4 = 0; c4 < CC / 4; ++c4) {
            float4 x = row4[c4];
            m = fmaxf(fmaxf(fmaxf(fmaxf(m, x.x), x.y), x.z), x.w);
        }
        float s = 0.f;
        for (int c4 = 0; c4 < CC / 4; ++c4) {
            float4 x = row4[c4];
            s += expf(x.x - m); s += expf(x.y - m);
            s += expf(x.z - m); s += expf(x.w - m);
        }
        lse_s[tid] = m + logf(s);
    }
    __syncthreads();                    // only barrier; all threads reach it

    if (w > 0) {
        // ================= producers: waves 1..3, rows (w-1)+3m ============
        const int start = w - 1;                    // 0,1,2
        const int count = (QQ - start + 2) / 3;     // 67,67,66

        // per-lane column constants (owned columns j = t+64k)
        int   cls[4];
        float tbx[4][4];
#pragma unroll
        for (int k = 0; k < 4; ++k) {
            if (k < nval) {
                int jj = t + 64 * k;
                cls[k] = tc[b * QQ + jj];
                const float4 v4 = *reinterpret_cast<const float4*>(tb + ((size_t)(b * QQ + jj)) * 4);
                tbx[k][0] = v4.x; tbx[k][1] = v4.y; tbx[k][2] = v4.z; tbx[k][3] = v4.w;
            } else {
                cls[k] = 0;
                tbx[k][0] = tbx[k][1] = tbx[k][2] = tbx[k][3] = 0.f;
            }
        }

        // identical per-element fp expression/order as R14
        for (int m = 0; m < count; ++m) {
            const int i = start + 3 * m;
            const float4 pb4 = *reinterpret_cast<const float4*>(pb + ((size_t)(b * QQ + i)) * 4);
            const float pbb[4] = {pb4.x, pb4.y, pb4.z, pb4.w};
            const float lsei = lse_s[i];
            const float* pcrow = pc + ((size_t)(b * QQ + i)) * CC;
#pragma unroll
            for (int k = 0; k < 4; ++k) {
                if (k < nval) {
                    float ce = lsei - pcrow[cls[k]];
                    float sl1 = 0.f;
#pragma unroll
                    for (int d = 0; d < 4; ++d) {
                        float df = pbb[d] - tbx[k][d];
                        float ad = fabsf(df);
                        sl1 += (ad < 1.f) ? 0.5f * df * df : (ad - 0.5f);
                    }
                    float mask = (cls[k] != 0) ? 1.f : 0.f;
                    cm[i * QQ + t + 64 * k] = ce + sl1 * mask;
                }
            }
            // drain this wave's LDS writes (lgkm only: global loads stay in
            // flight), then publish. "memory" clobber stops compiler motion.
            asm volatile("s_waitcnt lgkmcnt(0)" ::: "memory");
            if (t == 0) ((volatile int*)rdy)[i] = 1;
        }
        return;
    }

    // ================= consumer: wave 0, two-epoch R14 main loop ===========
    float v[4]     = {0.f, 0.f, 0.f, 0.f};
    int   pslot[4] = {0, 0, 0, 0};      // p for owned columns (0 = free)
    unsigned pp    = 0u;                // packed u8 shadow of pslot
    float uslot[4] = {0.f, 0.f, 0.f, 0.f};  // u of row matched to owned column
    float minv[4];
    int   waysl[4];
    int   usedm;
    float usent;
    int   watermark = 0;                // rows 0..watermark-1 known staged
    int   i = 1;

    // catch-up epoch: poll + clobber, only while rows are still landing
    for (; i <= QQ && watermark < QQ; ++i) {
        while (watermark < i) {
            int idx = watermark + t;
            int f = (idx < QQ) ? ((volatile int*)rdy)[idx] : 1;
            unsigned long long rm = __ballot(f != 0);
            unsigned long long nrm = ~rm;   // bit j set => lane j not ready
            int adv = nrm ? (int)__builtin_ctzll(nrm) : 64;
            if (adv == 0) __builtin_amdgcn_s_sleep(8);
            watermark += adv;
        }
        asm volatile("" ::: "memory");  // keep crow reads below the poll
        PHASE_BODY(i);
    }
    // steady epoch: all rows staged; no poll, no branch, no clobber --
    // R14's exact codegen freedom restored
    for (; i <= QQ; ++i) {
        PHASE_BODY(i);
    }

    // pslot[k] = row matched to owned column jc; emit per-row matched cost
#pragma unroll
    for (int k = 0; k < 4; ++k) {
        if (k < nval) {
            int jc = 1 + t + 64 * k;
            int row = pslot[k] - 1;
            out[b * QQ + row] = cm[row * QQ + (jc - 1)];
        }
    }
}

// ---------------------------------------------------------------------------
extern "C" void kernel_launch(void* const* d_in, const int* in_sizes, int n_in,
                              void* d_out, int out_size, void* d_ws, size_t ws_size,
                              hipStream_t stream) {
    const float* pred_cat  = (const float*)d_in[0];
    const float* pred_bbox = (const float*)d_in[1];
    const int*   tar_cat   = (const int*)d_in[2];
    const float* tar_bbox  = (const float*)d_in[3];
    float* out = (float*)d_out;
    (void)d_ws; (void)ws_size;

    hungarian_fused<<<BB, 256, 0, stream>>>(pred_cat, pred_bbox, tar_cat, tar_bbox, out);
}